// Round 17
// baseline (255.700 us; speedup 1.0000x reference)
//
#include <hip/hip_runtime.h>
#include <hip/hip_bf16.h>

typedef _Float16 half4_t __attribute__((ext_vector_type(4)));
typedef _Float16 half8 __attribute__((ext_vector_type(8)));
typedef float f32x4 __attribute__((ext_vector_type(4)));

#define BB 16
#define HH 64
#define WW2 64
#define CC 256

// ---------------------------------------------------------------------------
// Kernel PRE: fused preamble, 112 blocks (validated rounds 8-14).
// ---------------------------------------------------------------------------
__global__ __launch_bounds__(256) void k_pre(
    const float* __restrict__ Ww, const float* __restrict__ Wh,
    const float* __restrict__ pw,
    _Float16* __restrict__ WwT, _Float16* __restrict__ WhT,
    _Float16* __restrict__ pf, float* __restrict__ sums)
{
  __shared__ _Float16 tile[64][65];
  const int blk = blockIdx.x;
  const int t = threadIdx.x;

  if (blk < 32) {
    const int nt = blk & 3, kt = (blk >> 2) & 3, mat = blk >> 4;
    const float* src = mat ? Wh : Ww;
    _Float16* dst = mat ? WhT : WwT;
    const int n0 = nt * 64, k0 = kt * 64;
    const int sl = t & 63;
    #pragma unroll
    for (int p = 0; p < 16; p++) {
      int chl = (t >> 6) + p * 4;        // n-local
      tile[chl][sl] = (_Float16)src[(size_t)(n0 + chl) * 256 + k0 + sl];
    }
    __syncthreads();
    #pragma unroll
    for (int p = 0; p < 2; p++) {
      int pl = (t >> 3) + p * 32;        // k-local
      int c8 = (t & 7) * 8;              // n-local
      half8 hv;
      #pragma unroll
      for (int r = 0; r < 8; r++) hv[r] = tile[c8 + r][pl];
      *(half8*)(dst + (size_t)(k0 + pl) * 256 + n0 + c8) = hv;
    }
  } else if (blk < 80) {
    sums[(blk - 32) * 256 + t] = 0.f;    // 48*256 = 12288 floats
  } else {
    int i = (blk - 80) * 2048 + t * 8;   // 32*2048 = 65536 elems
    float4 v0 = *(const float4*)(pw + i);
    float4 v1 = *(const float4*)(pw + i + 4);
    half8 h = {(_Float16)v0.x, (_Float16)v0.y, (_Float16)v0.z, (_Float16)v0.w,
               (_Float16)v1.x, (_Float16)v1.y, (_Float16)v1.z, (_Float16)v1.w};
    *(half8*)(pf + i) = h;
  }
}

// ---------------------------------------------------------------------------
// Kernel TA: half-0 offset transpose + FUSED sw sampling (validated rounds
// 12/14 — standalone so it gets its own regalloc; round-15 merge squeezed it
// to 24 VGPR and cost +21us).
// ---------------------------------------------------------------------------
__global__ __launch_bounds__(256) void k_transA(
    const float* __restrict__ x, const float* __restrict__ off,
    _Float16* __restrict__ swb, float* __restrict__ ssw)
{
  __shared__ _Float16 tile[64][65];   // [ch_local][x] offsets
  __shared__ _Float16 xr[64][68];     // [x][ch_local]
  __shared__ float red[4][64];

  const int work = (blockIdx.x & 7) * 512 + (blockIdx.x >> 3);  // 4096 blocks
  const int st   = work & 63;          // y
  const int cht  = (work >> 6) & 3;
  const int b    = work >> 8;
  const int t = threadIdx.x;

  const int ch0 = cht * 64;
  const float* src = off + ((size_t)b * 512 + ch0) * 4096 + st * 64;
  const int sl = t & 63;
  #pragma unroll
  for (int p = 0; p < 16; p++) {
    int chl = (t >> 6) + p * 4;
    tile[chl][sl] = (_Float16)src[(size_t)chl * 4096 + sl];
  }

  // stage x row slice: xr[x][cl] = x[b, y=st, x, cht*64+cl]
  const float* xs_src = x + ((size_t)(b * 64 + st) * 64) * 256 + ch0;
  const int xrow = t >> 2;
  const int c16 = (t & 3) * 16;
  #pragma unroll
  for (int j = 0; j < 4; j++) {
    float4 v = *(const float4*)(xs_src + (size_t)xrow * 256 + c16 + j * 4);
    half4_t h = {(_Float16)v.x, (_Float16)v.y, (_Float16)v.z, (_Float16)v.w};
    *(half4_t*)(&xr[xrow][c16 + j * 4]) = h;
  }
  __syncthreads();

  // sample: thread = (xg, cl); 16 x's per thread
  const int cl = t & 63, xg = t >> 6;
  const int cg = ch0 + cl;
  _Float16* sp = swb + ((size_t)(b * 64 + st) * 64) * 256 + cg;
  float asw = 0.f;
  #pragma unroll
  for (int k = 0; k < 16; k++) {
    int xi = xg * 16 + k;
    float dx = (float)tile[cl][xi];
    float xs2 = (float)xi + dx;
    float xf = floorf(xs2);
    float wx = xs2 - xf;
    int xq = (int)xf;
    float v0 = (xq >= 0 && xq < 64) ? (float)xr[xq][cl] : 0.f;
    float v1 = (xq + 1 >= 0 && xq + 1 < 64) ? (float)xr[xq + 1][cl] : 0.f;
    float swv = (1.f - wx) * v0 + wx * v1;
    sp[(size_t)xi * 256] = (_Float16)swv;
    asw += swv;
  }
  red[xg][cl] = asw;
  __syncthreads();
  if (t < 64)
    atomicAdd(&ssw[b * CC + ch0 + t],
              red[0][t] + red[1][t] + red[2][t] + red[3][t]);
}

// ---------------------------------------------------------------------------
// Kernel TB: half-1 offset transpose -> offBT pixel-major (validated round 3).
// ---------------------------------------------------------------------------
__global__ __launch_bounds__(256) void k_transB(const float* __restrict__ off,
                                                _Float16* __restrict__ offBT)
{
  __shared__ _Float16 tile[64][65];
  const int work = (blockIdx.x & 7) * 512 + (blockIdx.x >> 3);  // 4096 blocks
  const int st   = work & 63;
  const int cht  = (work >> 6) & 3;
  const int b    = work >> 8;
  const int t = threadIdx.x;

  const int ch0 = 256 + cht * 64;
  const float* src = off + ((size_t)b * 512 + ch0) * 4096 + st * 64;
  const int sl = t & 63;
  #pragma unroll
  for (int p = 0; p < 16; p++) {
    int chl = (t >> 6) + p * 4;
    tile[chl][sl] = (_Float16)src[(size_t)chl * 4096 + sl];
  }
  __syncthreads();

  #pragma unroll
  for (int p = 0; p < 2; p++) {
    int pl = (t >> 3) + p * 32;
    int c8 = (t & 7) * 8;
    half8 hv;
    #pragma unroll
    for (int r = 0; r < 8; r++) hv[r] = tile[c8 + r][pl];
    int s = st * 64 + pl;
    size_t pix = (size_t)b * 4096 + (s & 63) * 64 + (s >> 6);
    *(half8*)(offBT + pix * 256 + cht * 64 + c8) = hv;
  }
}

// ---------------------------------------------------------------------------
// Kernel V: depthwise 5x5 conv, x-SPLIT (validated round 13).
// ---------------------------------------------------------------------------
__global__ __launch_bounds__(256) void k_conv(
    const float* __restrict__ x, const float* __restrict__ lw,
    _Float16* __restrict__ cvb, float* __restrict__ scv)
{
  const int work = (blockIdx.x & 7) * 256 + (blockIdx.x >> 3);  // 2048 blocks
  const int xh = work & 1;
  const int y  = (work >> 1) & 63;
  const int b  = work >> 7;
  const int c = threadIdx.x;

  float wgt[25];
  #pragma unroll
  for (int q = 0; q < 25; q++) wgt[q] = lw[c * 25 + q];

  const float* xb = x + (size_t)b * HH * WW2 * CC + c;
  const float* rp[5];
  bool yv[5];
  #pragma unroll
  for (int ky = 0; ky < 5; ky++) {
    int yy = y + ky - 2;
    yv[ky] = (yy >= 0 && yy < HH);
    rp[ky] = xb + (size_t)(yv[ky] ? yy : 0) * WW2 * CC;
  }

  _Float16* cp = cvb + ((size_t)b * 4096 + y * 64) * CC + c;
  float acv = 0.f;
  const int x0 = xh * 32;

  for (int g = 0; g < 4; ++g) {
    const int u0 = x0 + g * 8;
    float col[60];
    #pragma unroll
    for (int j = 0; j < 12; j++) {
      int xx = u0 + j - 2;
      bool xv = (xx >= 0 && xx < 64);
      int xxc = xv ? xx : 0;
      #pragma unroll
      for (int ky = 0; ky < 5; ky++) {
        float v = rp[ky][(size_t)xxc * CC];
        col[j * 5 + ky] = (xv && yv[ky]) ? v : 0.f;
      }
    }
    #pragma unroll
    for (int o = 0; o < 8; o++) {
      float cv = 0.f;
      #pragma unroll
      for (int kx = 0; kx < 5; kx++) {
        const int j5 = (o + kx) * 5;
        cv += wgt[0 + kx]  * col[j5 + 0] + wgt[5 + kx]  * col[j5 + 1] +
              wgt[10 + kx] * col[j5 + 2] + wgt[15 + kx] * col[j5 + 3] +
              wgt[20 + kx] * col[j5 + 4];
      }
      cp[(size_t)(u0 + o) * CC] = (_Float16)cv;
      acv += cv;
    }
  }
  atomicAdd(&scv[b * CC + c], acv);
}

// ---------------------------------------------------------------------------
// Kernel C: sh sampling, CHANNEL-SPLIT (validated round 13).
// ---------------------------------------------------------------------------
__global__ __launch_bounds__(256) void k_col(
    const float* __restrict__ x, const _Float16* __restrict__ offBT,
    _Float16* __restrict__ shb, float* __restrict__ ssh)
{
  __shared__ _Float16 xc[64 * 128];     // [y][cl], 16 KB
  const int work = (blockIdx.x & 7) * 256 + (blockIdx.x >> 3);  // 2048 blocks
  const int ch = work & 1;
  const int xi = (work >> 1) & 63;
  const int b  = work >> 7;
  const int ch0 = ch * 128;
  const int t = threadIdx.x;

  #pragma unroll
  for (int p = 0; p < 4; p++) {
    int i = p * 2048 + t * 8;           // f16 idx in [64*128)
    int yy = i >> 7, cl = i & 127;
    const float* s = x + ((size_t)(b * 64 + yy) * 64 + xi) * 256 + ch0 + cl;
    float4 v0 = *(const float4*)(s);
    float4 v1 = *(const float4*)(s + 4);
    half8 h = {(_Float16)v0.x, (_Float16)v0.y, (_Float16)v0.z, (_Float16)v0.w,
               (_Float16)v1.x, (_Float16)v1.y, (_Float16)v1.z, (_Float16)v1.w};
    *(half8*)(xc + i) = h;
  }
  __syncthreads();

  const int cl = t & 127, yg = t >> 7;
  const _Float16* obt = offBT + ((size_t)(b * 64 + xi) * 64) * 256 + ch0 + cl;
  _Float16* hp = shb + ((size_t)(b * 64) * 64 + xi) * 256 + ch0 + cl;
  float ash = 0.f;
  #pragma unroll 8
  for (int k = 0; k < 32; k++) {
    int yy = yg * 32 + k;
    float dy = (float)obt[(size_t)yy * 256];
    float ys = (float)yy + dy;
    float yf = floorf(ys);
    float wy = ys - yf;
    int yq = (int)yf;
    float u0 = (yq >= 0 && yq < 64) ? (float)xc[yq * 128 + cl] : 0.f;
    float u1 = (yq + 1 >= 0 && yq + 1 < 64) ? (float)xc[(yq + 1) * 128 + cl] : 0.f;
    float shv = (1.f - wy) * u0 + wy * u1;
    hp[(size_t)yy * 64 * 256] = (_Float16)shv;
    ash += shv;
  }
  atomicAdd(&ssh[b * CC + ch0 + cl], ash);
}

// ---------------------------------------------------------------------------
// Kernel B: gating MLP (validated round 7).
// ---------------------------------------------------------------------------
__global__ __launch_bounds__(256) void k_gate(
    const float* __restrict__ ssw, const float* __restrict__ ssh, const float* __restrict__ scv,
    const float* __restrict__ Ww, const float* __restrict__ bw,
    const float* __restrict__ Wh, const float* __restrict__ bh,
    const float* __restrict__ blc,
    const float* __restrict__ fc1w, const float* __restrict__ fc1b,
    const float* __restrict__ fc2w, const float* __restrict__ fc2b,
    _Float16* __restrict__ gh, float* __restrict__ bcomb)
{
  __shared__ float sswl[CC], sshl[CC], avgl[CC], tl[64];
  const int b = blockIdx.x, tid = threadIdx.x;
  sswl[tid] = ssw[b * CC + tid];
  sshl[tid] = ssh[b * CC + tid];
  __syncthreads();

  float acc = scv[b * CC + tid];
  for (int c = 0; c < CC; c++)
    acc += sswl[c] * Ww[tid * CC + c] + sshl[c] * Wh[tid * CC + c];
  avgl[tid] = acc * (1.f / (HH * WW2)) + bw[tid] + bh[tid] + blc[tid];
  __syncthreads();

  if (tid < 64) {
    float a = fc1b[tid];
    for (int o = 0; o < CC; o++) a += avgl[o] * fc1w[tid * CC + o];
    tl[tid] = 0.5f * a * (1.f + erff(a * 0.70710678118654752f));
  }
  __syncthreads();

  float g[3];
  #pragma unroll
  for (int j = 0; j < 3; j++) {
    float a = fc2b[tid * 3 + j];
    for (int k = 0; k < 64; k++) a += tl[k] * fc2w[(tid * 3 + j) * 64 + k];
    g[j] = a;
  }
  float m = fmaxf(g[0], fmaxf(g[1], g[2]));
  float e0 = expf(g[0] - m), e1 = expf(g[1] - m), e2 = expf(g[2] - m);
  float inv = 1.f / (e0 + e1 + e2);
  float a0 = e0 * inv, a1 = e1 * inv, a2 = e2 * inv;
  gh[(0 * BB + b) * CC + tid] = (_Float16)a0;
  gh[(1 * BB + b) * CC + tid] = (_Float16)a1;
  gh[(2 * BB + b) * CC + tid] = (_Float16)a2;
  bcomb[b * CC + tid] = a0 * bw[tid] + a1 * bh[tid] + a2 * blc[tid];
}

// ---------------------------------------------------------------------------
// Kernel M: build per-batch collapsed weights (validated round 7).
// ---------------------------------------------------------------------------
__global__ __launch_bounds__(256) void k_mats(
    const _Float16* __restrict__ pf, const _Float16* __restrict__ gh,
    const _Float16* __restrict__ WwT, const _Float16* __restrict__ WhT,
    const float* __restrict__ bcomb, const float* __restrict__ pb,
    _Float16* __restrict__ Bcat, float* __restrict__ bias_out)
{
  const int blk = (blockIdx.x & 7) * 16 + (blockIdx.x >> 3);  // 128 blocks
  const int ob = blk & 3;
  const int br = (blk >> 2) & 1;
  const int b  = blk >> 3;
  const int o0 = ob * 64;
  const int tid = threadIdx.x;
  const int wid = tid >> 6, l = tid & 63;
  const int n0 = wid * 64;             // k-column block
  const int lr = l & 15;
  const int kg = (l >> 4) * 8;
  const int jr = (l >> 4) * 4;

  const _Float16* WT  = br ? WhT : WwT;
  const _Float16* ghb = gh + (size_t)(br * BB + b) * CC;

  f32x4 acc[4][4];
  #pragma unroll
  for (int mi = 0; mi < 4; mi++)
    #pragma unroll
    for (int ni = 0; ni < 4; ni++) acc[mi][ni] = (f32x4){0.f, 0.f, 0.f, 0.f};

  #pragma unroll
  for (int ks = 0; ks < 8; ks++) {
    half8 gv = *(const half8*)(ghb + kg + ks * 32);
    half8 a[4], bbv[4];
    #pragma unroll
    for (int mi = 0; mi < 4; mi++)
      a[mi] = *(const half8*)(pf + (size_t)(o0 + mi * 16 + lr) * CC + kg + ks * 32) * gv;
    #pragma unroll
    for (int ni = 0; ni < 4; ni++)
      bbv[ni] = *(const half8*)(WT + (size_t)(n0 + ni * 16 + lr) * CC + kg + ks * 32);
    #pragma unroll
    for (int mi = 0; mi < 4; mi++)
      #pragma unroll
      for (int ni = 0; ni < 4; ni++)
        acc[mi][ni] = __builtin_amdgcn_mfma_f32_16x16x32_f16(a[mi], bbv[ni], acc[mi][ni], 0, 0, 0);
  }

  #pragma unroll
  for (int ni = 0; ni < 4; ni++) {
    int kcol = n0 + ni * 16 + lr;
    #pragma unroll
    for (int mi = 0; mi < 4; mi++) {
      #pragma unroll
      for (int j = 0; j < 4; j++) {
        int o = o0 + mi * 16 + jr + j;
        Bcat[((size_t)b * CC + o) * 512 + br * 256 + kcol] = (_Float16)acc[mi][ni][j];
      }
    }
  }

  if (br == 0) {
    int o_l = tid >> 2, part = tid & 3;
    const _Float16* pr = pf + (size_t)(o0 + o_l) * CC + part * 64;
    const float* bc = bcomb + b * CC + part * 64;
    float s = 0.f;
    #pragma unroll
    for (int i = 0; i < 8; i++) {
      half8 h = *(const half8*)(pr + i * 8);
      #pragma unroll
      for (int r = 0; r < 8; r++) s += (float)h[r] * bc[i * 8 + r];
    }
    s += __shfl_xor(s, 1);
    s += __shfl_xor(s, 2);
    if (part == 0) bias_out[b * CC + o0 + o_l] = s + pb[o0 + o_l];
  }
}

// ---------------------------------------------------------------------------
// Kernel G: single K=768 GEMM, 64-row tiles, DOUBLE-BUFFERED LDS (validated
// round 15: part of the -30us).
// ---------------------------------------------------------------------------
#define APAD 264
__global__ __launch_bounds__(256) void k_gemm(
    const _Float16* __restrict__ swb, const _Float16* __restrict__ shb,
    const _Float16* __restrict__ cvb, const _Float16* __restrict__ Bcat,
    const _Float16* __restrict__ pf, const _Float16* __restrict__ a2h,
    const float* __restrict__ bias_out, float* __restrict__ out)
{
  __shared__ _Float16 smem[2 * 64 * APAD];  // 67,584 B
  _Float16* buf0 = smem;
  _Float16* buf1 = smem + 64 * APAD;

  const int work = (blockIdx.x & 7) * 128 + (blockIdx.x >> 3);  // 1024 blocks
  const int r0 = work * 64;
  const int b = work >> 6;
  const int tid = threadIdx.x;
  const int wid = tid >> 6, l = tid & 63;
  const int n0 = wid * 64;
  const int lr = l & 15;
  const int kg = (l >> 4) * 8;
  const int jr = (l >> 4) * 4;

  const _Float16* bq = Bcat + ((size_t)b * CC + n0 + lr) * 512 + kg;

  f32x4 acc[4][4];
  #pragma unroll
  for (int mi = 0; mi < 4; mi++)
    #pragma unroll
    for (int ni = 0; ni < 4; ni++) acc[mi][ni] = (f32x4){0.f, 0.f, 0.f, 0.f};

  half8 st[8];
  // stage sw -> buf0
  {
    const _Float16* g = swb + (size_t)r0 * CC;
    #pragma unroll
    for (int p = 0; p < 8; p++) st[p] = *(const half8*)(g + p * 2048 + tid * 8);
    #pragma unroll
    for (int p = 0; p < 8; p++) {
      int i = p * 2048 + tid * 8;
      *(half8*)(buf0 + (i >> 8) * APAD + (i & 255)) = st[p];
    }
  }
  __syncthreads();
  // prefetch sh
  {
    const _Float16* g = shb + (size_t)r0 * CC;
    #pragma unroll
    for (int p = 0; p < 8; p++) st[p] = *(const half8*)(g + p * 2048 + tid * 8);
  }
  // ---- phase A: sw from buf0 ----
  #pragma unroll
  for (int ks = 0; ks < 8; ks++) {
    half8 a[4], bbv[4];
    #pragma unroll
    for (int mi = 0; mi < 4; mi++)
      a[mi] = *(const half8*)(buf0 + (mi * 16 + lr) * APAD + kg + ks * 32);
    #pragma unroll
    for (int ni = 0; ni < 4; ni++)
      bbv[ni] = *(const half8*)(bq + (size_t)ni * 16 * 512 + ks * 32);
    #pragma unroll
    for (int mi = 0; mi < 4; mi++)
      #pragma unroll
      for (int ni = 0; ni < 4; ni++)
        acc[mi][ni] = __builtin_amdgcn_mfma_f32_16x16x32_f16(a[mi], bbv[ni], acc[mi][ni], 0, 0, 0);
  }
  // store sh -> buf1 (not read until after the barrier)
  #pragma unroll
  for (int p = 0; p < 8; p++) {
    int i = p * 2048 + tid * 8;
    *(half8*)(buf1 + (i >> 8) * APAD + (i & 255)) = st[p];
  }
  __syncthreads();
  // prefetch cv
  {
    const _Float16* g = cvb + (size_t)r0 * CC;
    #pragma unroll
    for (int p = 0; p < 8; p++) st[p] = *(const half8*)(g + p * 2048 + tid * 8);
  }
  // ---- phase B: sh from buf1 (Bcat cols 256..511) ----
  #pragma unroll
  for (int ks = 0; ks < 8; ks++) {
    half8 a[4], bbv[4];
    #pragma unroll
    for (int mi = 0; mi < 4; mi++)
      a[mi] = *(const half8*)(buf1 + (mi * 16 + lr) * APAD + kg + ks * 32);
    #pragma unroll
    for (int ni = 0; ni < 4; ni++)
      bbv[ni] = *(const half8*)(bq + (size_t)ni * 16 * 512 + 256 + ks * 32);
    #pragma unroll
    for (int mi = 0; mi < 4; mi++)
      #pragma unroll
      for (int ni = 0; ni < 4; ni++)
        acc[mi][ni] = __builtin_amdgcn_mfma_f32_16x16x32_f16(a[mi], bbv[ni], acc[mi][ni], 0, 0, 0);
  }
  // store cv -> buf0 (phase-A readers finished at previous barrier)
  #pragma unroll
  for (int p = 0; p < 8; p++) {
    int i = p * 2048 + tid * 8;
    *(half8*)(buf0 + (i >> 8) * APAD + (i & 255)) = st[p];
  }
  __syncthreads();
  // ---- phase C: cv from buf0, B-frag = pf * a2 on the fly ----
  const _Float16* a2b = a2h + (size_t)b * CC;
  #pragma unroll
  for (int ks = 0; ks < 8; ks++) {
    half8 a2v = *(const half8*)(a2b + kg + ks * 32);
    half8 a[4], bbv[4];
    #pragma unroll
    for (int mi = 0; mi < 4; mi++)
      a[mi] = *(const half8*)(buf0 + (mi * 16 + lr) * APAD + kg + ks * 32);
    #pragma unroll
    for (int ni = 0; ni < 4; ni++)
      bbv[ni] = *(const half8*)(pf + (size_t)(n0 + ni * 16 + lr) * CC + kg + ks * 32) * a2v;
    #pragma unroll
    for (int mi = 0; mi < 4; mi++)
      #pragma unroll
      for (int ni = 0; ni < 4; ni++)
        acc[mi][ni] = __builtin_amdgcn_mfma_f32_16x16x32_f16(a[mi], bbv[ni], acc[mi][ni], 0, 0, 0);
  }

  // epilogue
  #pragma unroll
  for (int ni = 0; ni < 4; ni++) {
    int col = n0 + ni * 16 + lr;
    float bo = bias_out[b * CC + col];
    #pragma unroll
    for (int mi = 0; mi < 4; mi++) {
      #pragma unroll
      for (int j = 0; j < 4; j++) {
        size_t idx = (size_t)(r0 + mi * 16 + jr + j) * CC + col;
        out[idx] = acc[mi][ni][j] + bo;
      }
    }
  }
}

// ---------------------------------------------------------------------------
extern "C" void kernel_launch(void* const* d_in, const int* in_sizes, int n_in,
                              void* d_out, int out_size, void* d_ws, size_t ws_size,
                              hipStream_t stream)
{
  const float* x    = (const float*)d_in[0];
  const float* off  = (const float*)d_in[1];
  const float* Ww   = (const float*)d_in[2];
  const float* bw   = (const float*)d_in[3];
  const float* Wh   = (const float*)d_in[4];
  const float* bh   = (const float*)d_in[5];
  const float* lw   = (const float*)d_in[6];
  const float* blc  = (const float*)d_in[7];
  const float* fc1w = (const float*)d_in[8];
  const float* fc1b = (const float*)d_in[9];
  const float* fc2w = (const float*)d_in[10];
  const float* fc2b = (const float*)d_in[11];
  const float* pw   = (const float*)d_in[12];
  const float* pb   = (const float*)d_in[13];
  float* out = (float*)d_out;

  char* ws = (char*)d_ws;
  // ws regions, all disjoint (validated round 12, footprint 138.6 MB):
  _Float16* shb   = (_Float16*)(ws + 0);
  _Float16* cvb   = (_Float16*)(ws + 33554432);
  _Float16* offBT = (_Float16*)(ws + 67108864);
  _Float16* swb   = (_Float16*)(ws + 100663296);
  _Float16* Bcat  = (_Float16*)(ws + 134217728);  // 4 MiB
  _Float16* pf    = (_Float16*)(ws + 138412032);  // 131,072 B
  _Float16* gh    = (_Float16*)(ws + 138543104);  //  24,576 B
  float* bcomb    = (float*)(ws + 138567680);     //  16,384 B
  float* bias_out = (float*)(ws + 138584064);     //  16,384 B
  // d_out scratch (consumed before k_gemm writes out):
  _Float16* WwT = (_Float16*)((char*)d_out + 0);        // 131,072 B
  _Float16* WhT = (_Float16*)((char*)d_out + 131072);   // 131,072 B
  float* sums   = (float*)((char*)d_out + 262144);      //  49,152 B
  float* ssw = sums, *ssh = sums + 4096, *scv = sums + 8192;

  k_pre<<<112, 256, 0, stream>>>(Ww, Wh, pw, WwT, WhT, pf, sums);
  k_transB<<<4096, 256, 0, stream>>>(off, offBT);
  k_col<<<2048, 256, 0, stream>>>(x, offBT, shb, ssh);
  k_transA<<<4096, 256, 0, stream>>>(x, off, swb, ssw);
  k_conv<<<2048, 256, 0, stream>>>(x, lw, cvb, scv);
  k_gate<<<BB, 256, 0, stream>>>(ssw, ssh, scv, Ww, bw, Wh, bh, blc,
                                 fc1w, fc1b, fc2w, fc2b, gh, bcomb);
  k_mats<<<128, 256, 0, stream>>>(pf, gh, WwT, WhT, bcomb, pb, Bcat, bias_out);
  k_gemm<<<1024, 256, 0, stream>>>(swb, shb, cvb, Bcat, pf, gh + 2 * BB * CC,
                                   bias_out, out);
}

// Round 18
// 245.098 us; speedup vs baseline: 1.0433x; 1.0433x over previous
//
#include <hip/hip_runtime.h>
#include <hip/hip_bf16.h>

typedef _Float16 half4_t __attribute__((ext_vector_type(4)));
typedef _Float16 half8 __attribute__((ext_vector_type(8)));
typedef float f32x4 __attribute__((ext_vector_type(4)));

#define BB 16
#define HH 64
#define WW2 64
#define CC 256

// ---------------------------------------------------------------------------
// Kernel STAGE: merged light-register stage-1 (8288 blocks) — round-15
// validated config (measured best, 246.7us total). ONE change: launch_bounds
// min-waves = 2 frees the register allocator (default heuristic chose 24
// VGPR, strangling the transA sampling branch's ILP; LDS caps occupancy at
// 8 blocks/CU regardless, and 2 blocks/CU suffices for streaming).
// ---------------------------------------------------------------------------
__global__ __launch_bounds__(256, 2) void k_stage(
    const float* __restrict__ x, const float* __restrict__ off,
    const float* __restrict__ Ww, const float* __restrict__ Wh,
    const float* __restrict__ pw,
    _Float16* __restrict__ swb, _Float16* __restrict__ offBT,
    _Float16* __restrict__ WwT, _Float16* __restrict__ WhT,
    _Float16* __restrict__ pf,
    float* __restrict__ sswp, float* __restrict__ zbase)
{
  __shared__ _Float16 tile[64][65];
  __shared__ _Float16 xr[64][68];
  __shared__ float red[4][64];

  const int work = (blockIdx.x & 7) * 1036 + (blockIdx.x >> 3);  // 8288 blocks
  const int t = threadIdx.x;

  if (work < 4096) {
    // ---- transA: offset transpose + fused sw sampling ----
    const int st   = work & 63;          // y
    const int cht  = (work >> 6) & 3;
    const int b    = work >> 8;
    const int ch0 = cht * 64;
    const float* src = off + ((size_t)b * 512 + ch0) * 4096 + st * 64;
    const int sl = t & 63;
    #pragma unroll
    for (int p = 0; p < 16; p++) {
      int chl = (t >> 6) + p * 4;
      tile[chl][sl] = (_Float16)src[(size_t)chl * 4096 + sl];
    }
    const float* xs_src = x + ((size_t)(b * 64 + st) * 64) * 256 + ch0;
    const int xrow = t >> 2;
    const int c16 = (t & 3) * 16;
    #pragma unroll
    for (int j = 0; j < 4; j++) {
      float4 v = *(const float4*)(xs_src + (size_t)xrow * 256 + c16 + j * 4);
      half4_t h = {(_Float16)v.x, (_Float16)v.y, (_Float16)v.z, (_Float16)v.w};
      *(half4_t*)(&xr[xrow][c16 + j * 4]) = h;
    }
    __syncthreads();

    const int cl = t & 63, xg = t >> 6;
    _Float16* sp = swb + ((size_t)(b * 64 + st) * 64) * 256 + ch0 + cl;
    float asw = 0.f;
    #pragma unroll
    for (int k = 0; k < 16; k++) {
      int xi = xg * 16 + k;
      float dx = (float)tile[cl][xi];
      float xs2 = (float)xi + dx;
      float xf = floorf(xs2);
      float wx = xs2 - xf;
      int xq = (int)xf;
      float v0 = (xq >= 0 && xq < 64) ? (float)xr[xq][cl] : 0.f;
      float v1 = (xq + 1 >= 0 && xq + 1 < 64) ? (float)xr[xq + 1][cl] : 0.f;
      float swv = (1.f - wx) * v0 + wx * v1;
      sp[(size_t)xi * 256] = (_Float16)swv;
      asw += swv;
    }
    red[xg][cl] = asw;
    __syncthreads();
    if (t < 64)
      sswp[((size_t)(b * 64 + st)) * 256 + ch0 + t] =
          red[0][t] + red[1][t] + red[2][t] + red[3][t];
  } else if (work < 8192) {
    // ---- transB: offset transpose -> offBT pixel-major ----
    const int w2 = work - 4096;
    const int st   = w2 & 63;
    const int cht  = (w2 >> 6) & 3;
    const int b    = w2 >> 8;
    const int ch0 = 256 + cht * 64;
    const float* src = off + ((size_t)b * 512 + ch0) * 4096 + st * 64;
    const int sl = t & 63;
    #pragma unroll
    for (int p = 0; p < 16; p++) {
      int chl = (t >> 6) + p * 4;
      tile[chl][sl] = (_Float16)src[(size_t)chl * 4096 + sl];
    }
    __syncthreads();
    #pragma unroll
    for (int p = 0; p < 2; p++) {
      int pl = (t >> 3) + p * 32;
      int c8 = (t & 7) * 8;
      half8 hv;
      #pragma unroll
      for (int r = 0; r < 8; r++) hv[r] = tile[c8 + r][pl];
      int s = st * 64 + pl;
      size_t pix = (size_t)b * 4096 + (s & 63) * 64 + (s >> 6);
      *(half8*)(offBT + pix * 256 + cht * 64 + c8) = hv;
    }
  } else if (work < 8224) {
    // ---- Ww/Wh transpose -> f16 [k][n] ----
    const int w3 = work - 8192;
    const int nt = w3 & 3, kt = (w3 >> 2) & 3, mat = w3 >> 4;
    const float* src = mat ? Wh : Ww;
    _Float16* dst = mat ? WhT : WwT;
    const int n0 = nt * 64, k0 = kt * 64;
    const int sl = t & 63;
    #pragma unroll
    for (int p = 0; p < 16; p++) {
      int chl = (t >> 6) + p * 4;
      tile[chl][sl] = (_Float16)src[(size_t)(n0 + chl) * 256 + k0 + sl];
    }
    __syncthreads();
    #pragma unroll
    for (int p = 0; p < 2; p++) {
      int pl = (t >> 3) + p * 32;
      int c8 = (t & 7) * 8;
      half8 hv;
      #pragma unroll
      for (int r = 0; r < 8; r++) hv[r] = tile[c8 + r][pl];
      *(half8*)(dst + (size_t)(k0 + pl) * 256 + n0 + c8) = hv;
    }
  } else if (work < 8256) {
    // ---- pw -> pf f16 ----
    int i = (work - 8224) * 2048 + t * 8;
    float4 v0 = *(const float4*)(pw + i);
    float4 v1 = *(const float4*)(pw + i + 4);
    half8 h = {(_Float16)v0.x, (_Float16)v0.y, (_Float16)v0.z, (_Float16)v0.w,
               (_Float16)v1.x, (_Float16)v1.y, (_Float16)v1.z, (_Float16)v1.w};
    *(half8*)(pf + i) = h;
  } else {
    // ---- zero ssh+scv (8192 floats) ----
    zbase[(work - 8256) * 256 + t] = 0.f;
  }
}

// ---------------------------------------------------------------------------
// Kernel V: depthwise 5x5 conv, x-SPLIT (validated round 13).
// ---------------------------------------------------------------------------
__global__ __launch_bounds__(256) void k_conv(
    const float* __restrict__ x, const float* __restrict__ lw,
    _Float16* __restrict__ cvb, float* __restrict__ scv)
{
  const int work = (blockIdx.x & 7) * 256 + (blockIdx.x >> 3);  // 2048 blocks
  const int xh = work & 1;
  const int y  = (work >> 1) & 63;
  const int b  = work >> 7;
  const int c = threadIdx.x;

  float wgt[25];
  #pragma unroll
  for (int q = 0; q < 25; q++) wgt[q] = lw[c * 25 + q];

  const float* xb = x + (size_t)b * HH * WW2 * CC + c;
  const float* rp[5];
  bool yv[5];
  #pragma unroll
  for (int ky = 0; ky < 5; ky++) {
    int yy = y + ky - 2;
    yv[ky] = (yy >= 0 && yy < HH);
    rp[ky] = xb + (size_t)(yv[ky] ? yy : 0) * WW2 * CC;
  }

  _Float16* cp = cvb + ((size_t)b * 4096 + y * 64) * CC + c;
  float acv = 0.f;
  const int x0 = xh * 32;

  for (int g = 0; g < 4; ++g) {
    const int u0 = x0 + g * 8;
    float col[60];
    #pragma unroll
    for (int j = 0; j < 12; j++) {
      int xx = u0 + j - 2;
      bool xv = (xx >= 0 && xx < 64);
      int xxc = xv ? xx : 0;
      #pragma unroll
      for (int ky = 0; ky < 5; ky++) {
        float v = rp[ky][(size_t)xxc * CC];
        col[j * 5 + ky] = (xv && yv[ky]) ? v : 0.f;
      }
    }
    #pragma unroll
    for (int o = 0; o < 8; o++) {
      float cv = 0.f;
      #pragma unroll
      for (int kx = 0; kx < 5; kx++) {
        const int j5 = (o + kx) * 5;
        cv += wgt[0 + kx]  * col[j5 + 0] + wgt[5 + kx]  * col[j5 + 1] +
              wgt[10 + kx] * col[j5 + 2] + wgt[15 + kx] * col[j5 + 3] +
              wgt[20 + kx] * col[j5 + 4];
      }
      cp[(size_t)(u0 + o) * CC] = (_Float16)cv;
      acv += cv;
    }
  }
  atomicAdd(&scv[b * CC + c], acv);
}

// ---------------------------------------------------------------------------
// Kernel C: sh sampling, CHANNEL-SPLIT (validated round 13).
// ---------------------------------------------------------------------------
__global__ __launch_bounds__(256) void k_col(
    const float* __restrict__ x, const _Float16* __restrict__ offBT,
    _Float16* __restrict__ shb, float* __restrict__ ssh)
{
  __shared__ _Float16 xc[64 * 128];     // [y][cl], 16 KB
  const int work = (blockIdx.x & 7) * 256 + (blockIdx.x >> 3);  // 2048 blocks
  const int ch = work & 1;
  const int xi = (work >> 1) & 63;
  const int b  = work >> 7;
  const int ch0 = ch * 128;
  const int t = threadIdx.x;

  #pragma unroll
  for (int p = 0; p < 4; p++) {
    int i = p * 2048 + t * 8;           // f16 idx in [64*128)
    int yy = i >> 7, cl = i & 127;
    const float* s = x + ((size_t)(b * 64 + yy) * 64 + xi) * 256 + ch0 + cl;
    float4 v0 = *(const float4*)(s);
    float4 v1 = *(const float4*)(s + 4);
    half8 h = {(_Float16)v0.x, (_Float16)v0.y, (_Float16)v0.z, (_Float16)v0.w,
               (_Float16)v1.x, (_Float16)v1.y, (_Float16)v1.z, (_Float16)v1.w};
    *(half8*)(xc + i) = h;
  }
  __syncthreads();

  const int cl = t & 127, yg = t >> 7;
  const _Float16* obt = offBT + ((size_t)(b * 64 + xi) * 64) * 256 + ch0 + cl;
  _Float16* hp = shb + ((size_t)(b * 64) * 64 + xi) * 256 + ch0 + cl;
  float ash = 0.f;
  #pragma unroll 8
  for (int k = 0; k < 32; k++) {
    int yy = yg * 32 + k;
    float dy = (float)obt[(size_t)yy * 256];
    float ys = (float)yy + dy;
    float yf = floorf(ys);
    float wy = ys - yf;
    int yq = (int)yf;
    float u0 = (yq >= 0 && yq < 64) ? (float)xc[yq * 128 + cl] : 0.f;
    float u1 = (yq + 1 >= 0 && yq + 1 < 64) ? (float)xc[(yq + 1) * 128 + cl] : 0.f;
    float shv = (1.f - wy) * u0 + wy * u1;
    hp[(size_t)yy * 64 * 256] = (_Float16)shv;
    ash += shv;
  }
  atomicAdd(&ssh[b * CC + ch0 + cl], ash);
}

// ---------------------------------------------------------------------------
// Kernel B: gating MLP; ssw from per-row partials, ssh/scv from atomics
// (validated round 15).
// ---------------------------------------------------------------------------
__global__ __launch_bounds__(256) void k_gate(
    const float* __restrict__ sswp, const float* __restrict__ ssh,
    const float* __restrict__ scv,
    const float* __restrict__ Ww, const float* __restrict__ bw,
    const float* __restrict__ Wh, const float* __restrict__ bh,
    const float* __restrict__ blc,
    const float* __restrict__ fc1w, const float* __restrict__ fc1b,
    const float* __restrict__ fc2w, const float* __restrict__ fc2b,
    _Float16* __restrict__ gh, float* __restrict__ bcomb)
{
  __shared__ float sswl[CC], sshl[CC], avgl[CC], tl[64];
  const int b = blockIdx.x, tid = threadIdx.x;

  float s_sw = 0.f;
  for (int q = 0; q < 64; q++)
    s_sw += sswp[((size_t)(b * 64 + q)) * 256 + tid];
  sswl[tid] = s_sw;
  sshl[tid] = ssh[b * CC + tid];
  __syncthreads();

  float acc = scv[b * CC + tid];
  for (int c = 0; c < CC; c++)
    acc += sswl[c] * Ww[tid * CC + c] + sshl[c] * Wh[tid * CC + c];
  avgl[tid] = acc * (1.f / (HH * WW2)) + bw[tid] + bh[tid] + blc[tid];
  __syncthreads();

  if (tid < 64) {
    float a = fc1b[tid];
    for (int o = 0; o < CC; o++) a += avgl[o] * fc1w[tid * CC + o];
    tl[tid] = 0.5f * a * (1.f + erff(a * 0.70710678118654752f));
  }
  __syncthreads();

  float g[3];
  #pragma unroll
  for (int j = 0; j < 3; j++) {
    float a = fc2b[tid * 3 + j];
    for (int k = 0; k < 64; k++) a += tl[k] * fc2w[(tid * 3 + j) * 64 + k];
    g[j] = a;
  }
  float m = fmaxf(g[0], fmaxf(g[1], g[2]));
  float e0 = expf(g[0] - m), e1 = expf(g[1] - m), e2 = expf(g[2] - m);
  float inv = 1.f / (e0 + e1 + e2);
  float a0 = e0 * inv, a1 = e1 * inv, a2 = e2 * inv;
  gh[(0 * BB + b) * CC + tid] = (_Float16)a0;
  gh[(1 * BB + b) * CC + tid] = (_Float16)a1;
  gh[(2 * BB + b) * CC + tid] = (_Float16)a2;
  bcomb[b * CC + tid] = a0 * bw[tid] + a1 * bh[tid] + a2 * blc[tid];
}

// ---------------------------------------------------------------------------
// Kernel M: build per-batch collapsed weights (validated round 7).
// ---------------------------------------------------------------------------
__global__ __launch_bounds__(256) void k_mats(
    const _Float16* __restrict__ pf, const _Float16* __restrict__ gh,
    const _Float16* __restrict__ WwT, const _Float16* __restrict__ WhT,
    const float* __restrict__ bcomb, const float* __restrict__ pb,
    _Float16* __restrict__ Bcat, float* __restrict__ bias_out)
{
  const int blk = (blockIdx.x & 7) * 16 + (blockIdx.x >> 3);  // 128 blocks
  const int ob = blk & 3;
  const int br = (blk >> 2) & 1;
  const int b  = blk >> 3;
  const int o0 = ob * 64;
  const int tid = threadIdx.x;
  const int wid = tid >> 6, l = tid & 63;
  const int n0 = wid * 64;             // k-column block
  const int lr = l & 15;
  const int kg = (l >> 4) * 8;
  const int jr = (l >> 4) * 4;

  const _Float16* WT  = br ? WhT : WwT;
  const _Float16* ghb = gh + (size_t)(br * BB + b) * CC;

  f32x4 acc[4][4];
  #pragma unroll
  for (int mi = 0; mi < 4; mi++)
    #pragma unroll
    for (int ni = 0; ni < 4; ni++) acc[mi][ni] = (f32x4){0.f, 0.f, 0.f, 0.f};

  #pragma unroll
  for (int ks = 0; ks < 8; ks++) {
    half8 gv = *(const half8*)(ghb + kg + ks * 32);
    half8 a[4], bbv[4];
    #pragma unroll
    for (int mi = 0; mi < 4; mi++)
      a[mi] = *(const half8*)(pf + (size_t)(o0 + mi * 16 + lr) * CC + kg + ks * 32) * gv;
    #pragma unroll
    for (int ni = 0; ni < 4; ni++)
      bbv[ni] = *(const half8*)(WT + (size_t)(n0 + ni * 16 + lr) * CC + kg + ks * 32);
    #pragma unroll
    for (int mi = 0; mi < 4; mi++)
      #pragma unroll
      for (int ni = 0; ni < 4; ni++)
        acc[mi][ni] = __builtin_amdgcn_mfma_f32_16x16x32_f16(a[mi], bbv[ni], acc[mi][ni], 0, 0, 0);
  }

  #pragma unroll
  for (int ni = 0; ni < 4; ni++) {
    int kcol = n0 + ni * 16 + lr;
    #pragma unroll
    for (int mi = 0; mi < 4; mi++) {
      #pragma unroll
      for (int j = 0; j < 4; j++) {
        int o = o0 + mi * 16 + jr + j;
        Bcat[((size_t)b * CC + o) * 512 + br * 256 + kcol] = (_Float16)acc[mi][ni][j];
      }
    }
  }

  if (br == 0) {
    int o_l = tid >> 2, part = tid & 3;
    const _Float16* pr = pf + (size_t)(o0 + o_l) * CC + part * 64;
    const float* bc = bcomb + b * CC + part * 64;
    float s = 0.f;
    #pragma unroll
    for (int i = 0; i < 8; i++) {
      half8 h = *(const half8*)(pr + i * 8);
      #pragma unroll
      for (int r = 0; r < 8; r++) s += (float)h[r] * bc[i * 8 + r];
    }
    s += __shfl_xor(s, 1);
    s += __shfl_xor(s, 2);
    if (part == 0) bias_out[b * CC + o0 + o_l] = s + pb[o0 + o_l];
  }
}

// ---------------------------------------------------------------------------
// Kernel G: single K=768 GEMM, 64-row tiles, DOUBLE-BUFFERED LDS (round 15).
// ---------------------------------------------------------------------------
#define APAD 264
__global__ __launch_bounds__(256) void k_gemm(
    const _Float16* __restrict__ swb, const _Float16* __restrict__ shb,
    const _Float16* __restrict__ cvb, const _Float16* __restrict__ Bcat,
    const _Float16* __restrict__ pf, const _Float16* __restrict__ a2h,
    const float* __restrict__ bias_out, float* __restrict__ out)
{
  __shared__ _Float16 smem[2 * 64 * APAD];  // 67,584 B
  _Float16* buf0 = smem;
  _Float16* buf1 = smem + 64 * APAD;

  const int work = (blockIdx.x & 7) * 128 + (blockIdx.x >> 3);  // 1024 blocks
  const int r0 = work * 64;
  const int b = work >> 6;
  const int tid = threadIdx.x;
  const int wid = tid >> 6, l = tid & 63;
  const int n0 = wid * 64;
  const int lr = l & 15;
  const int kg = (l >> 4) * 8;
  const int jr = (l >> 4) * 4;

  const _Float16* bq = Bcat + ((size_t)b * CC + n0 + lr) * 512 + kg;

  f32x4 acc[4][4];
  #pragma unroll
  for (int mi = 0; mi < 4; mi++)
    #pragma unroll
    for (int ni = 0; ni < 4; ni++) acc[mi][ni] = (f32x4){0.f, 0.f, 0.f, 0.f};

  half8 st[8];
  // stage sw -> buf0
  {
    const _Float16* g = swb + (size_t)r0 * CC;
    #pragma unroll
    for (int p = 0; p < 8; p++) st[p] = *(const half8*)(g + p * 2048 + tid * 8);
    #pragma unroll
    for (int p = 0; p < 8; p++) {
      int i = p * 2048 + tid * 8;
      *(half8*)(buf0 + (i >> 8) * APAD + (i & 255)) = st[p];
    }
  }
  __syncthreads();
  // prefetch sh
  {
    const _Float16* g = shb + (size_t)r0 * CC;
    #pragma unroll
    for (int p = 0; p < 8; p++) st[p] = *(const half8*)(g + p * 2048 + tid * 8);
  }
  // ---- phase A: sw from buf0 ----
  #pragma unroll
  for (int ks = 0; ks < 8; ks++) {
    half8 a[4], bbv[4];
    #pragma unroll
    for (int mi = 0; mi < 4; mi++)
      a[mi] = *(const half8*)(buf0 + (mi * 16 + lr) * APAD + kg + ks * 32);
    #pragma unroll
    for (int ni = 0; ni < 4; ni++)
      bbv[ni] = *(const half8*)(bq + (size_t)ni * 16 * 512 + ks * 32);
    #pragma unroll
    for (int mi = 0; mi < 4; mi++)
      #pragma unroll
      for (int ni = 0; ni < 4; ni++)
        acc[mi][ni] = __builtin_amdgcn_mfma_f32_16x16x32_f16(a[mi], bbv[ni], acc[mi][ni], 0, 0, 0);
  }
  // store sh -> buf1 (not read until after the barrier)
  #pragma unroll
  for (int p = 0; p < 8; p++) {
    int i = p * 2048 + tid * 8;
    *(half8*)(buf1 + (i >> 8) * APAD + (i & 255)) = st[p];
  }
  __syncthreads();
  // prefetch cv
  {
    const _Float16* g = cvb + (size_t)r0 * CC;
    #pragma unroll
    for (int p = 0; p < 8; p++) st[p] = *(const half8*)(g + p * 2048 + tid * 8);
  }
  // ---- phase B: sh from buf1 (Bcat cols 256..511) ----
  #pragma unroll
  for (int ks = 0; ks < 8; ks++) {
    half8 a[4], bbv[4];
    #pragma unroll
    for (int mi = 0; mi < 4; mi++)
      a[mi] = *(const half8*)(buf1 + (mi * 16 + lr) * APAD + kg + ks * 32);
    #pragma unroll
    for (int ni = 0; ni < 4; ni++)
      bbv[ni] = *(const half8*)(bq + (size_t)ni * 16 * 512 + 256 + ks * 32);
    #pragma unroll
    for (int mi = 0; mi < 4; mi++)
      #pragma unroll
      for (int ni = 0; ni < 4; ni++)
        acc[mi][ni] = __builtin_amdgcn_mfma_f32_16x16x32_f16(a[mi], bbv[ni], acc[mi][ni], 0, 0, 0);
  }
  // store cv -> buf0 (phase-A readers finished at previous barrier)
  #pragma unroll
  for (int p = 0; p < 8; p++) {
    int i = p * 2048 + tid * 8;
    *(half8*)(buf0 + (i >> 8) * APAD + (i & 255)) = st[p];
  }
  __syncthreads();
  // ---- phase C: cv from buf0, B-frag = pf * a2 on the fly ----
  const _Float16* a2b = a2h + (size_t)b * CC;
  #pragma unroll
  for (int ks = 0; ks < 8; ks++) {
    half8 a2v = *(const half8*)(a2b + kg + ks * 32);
    half8 a[4], bbv[4];
    #pragma unroll
    for (int mi = 0; mi < 4; mi++)
      a[mi] = *(const half8*)(buf0 + (mi * 16 + lr) * APAD + kg + ks * 32);
    #pragma unroll
    for (int ni = 0; ni < 4; ni++)
      bbv[ni] = *(const half8*)(pf + (size_t)(n0 + ni * 16 + lr) * CC + kg + ks * 32) * a2v;
    #pragma unroll
    for (int mi = 0; mi < 4; mi++)
      #pragma unroll
      for (int ni = 0; ni < 4; ni++)
        acc[mi][ni] = __builtin_amdgcn_mfma_f32_16x16x32_f16(a[mi], bbv[ni], acc[mi][ni], 0, 0, 0);
  }

  // epilogue
  #pragma unroll
  for (int ni = 0; ni < 4; ni++) {
    int col = n0 + ni * 16 + lr;
    float bo = bias_out[b * CC + col];
    #pragma unroll
    for (int mi = 0; mi < 4; mi++) {
      #pragma unroll
      for (int j = 0; j < 4; j++) {
        size_t idx = (size_t)(r0 + mi * 16 + jr + j) * CC + col;
        out[idx] = acc[mi][ni][j] + bo;
      }
    }
  }
}

// ---------------------------------------------------------------------------
extern "C" void kernel_launch(void* const* d_in, const int* in_sizes, int n_in,
                              void* d_out, int out_size, void* d_ws, size_t ws_size,
                              hipStream_t stream)
{
  const float* x    = (const float*)d_in[0];
  const float* off  = (const float*)d_in[1];
  const float* Ww   = (const float*)d_in[2];
  const float* bw   = (const float*)d_in[3];
  const float* Wh   = (const float*)d_in[4];
  const float* bh   = (const float*)d_in[5];
  const float* lw   = (const float*)d_in[6];
  const float* blc  = (const float*)d_in[7];
  const float* fc1w = (const float*)d_in[8];
  const float* fc1b = (const float*)d_in[9];
  const float* fc2w = (const float*)d_in[10];
  const float* fc2b = (const float*)d_in[11];
  const float* pw   = (const float*)d_in[12];
  const float* pb   = (const float*)d_in[13];
  float* out = (float*)d_out;

  char* ws = (char*)d_ws;
  // ws regions, all disjoint (validated round 12/15, footprint 138.6 MB):
  _Float16* shb   = (_Float16*)(ws + 0);
  _Float16* cvb   = (_Float16*)(ws + 33554432);
  _Float16* offBT = (_Float16*)(ws + 67108864);
  _Float16* swb   = (_Float16*)(ws + 100663296);
  _Float16* Bcat  = (_Float16*)(ws + 134217728);  // 4 MiB
  _Float16* pf    = (_Float16*)(ws + 138412032);  // 131,072 B
  _Float16* gh    = (_Float16*)(ws + 138543104);  //  24,576 B
  float* bcomb    = (float*)(ws + 138567680);     //  16,384 B
  float* bias_out = (float*)(ws + 138584064);     //  16,384 B
  // d_out scratch (all consumed by k_gate/k_mats before k_gemm writes out):
  _Float16* WwT = (_Float16*)((char*)d_out + 0);        // 131,072 B
  _Float16* WhT = (_Float16*)((char*)d_out + 131072);   // 131,072 B
  float* sums   = (float*)((char*)d_out + 262144);      //  49,152 B
  float* sswp   = (float*)((char*)d_out + 311296);      // 1,048,576 B partials
  float* ssh = sums + 4096, *scv = sums + 8192;

  k_stage<<<8288, 256, 0, stream>>>(x, off, Ww, Wh, pw,
                                    swb, offBT, WwT, WhT, pf,
                                    sswp, ssh /* zero base: ssh..scv end */);
  k_col<<<2048, 256, 0, stream>>>(x, offBT, shb, ssh);
  k_conv<<<2048, 256, 0, stream>>>(x, lw, cvb, scv);
  k_gate<<<BB, 256, 0, stream>>>(sswp, ssh, scv, Ww, bw, Wh, bh, blc,
                                 fc1w, fc1b, fc2w, fc2b, gh, bcomb);
  k_mats<<<128, 256, 0, stream>>>(pf, gh, WwT, WhT, bcomb, pb, Bcat, bias_out);
  k_gemm<<<1024, 256, 0, stream>>>(swb, shb, cvb, Bcat, pf, gh + 2 * BB * CC,
                                   bias_out, out);
}